// Round 1
// baseline (235.797 us; speedup 1.0000x reference)
//
#include <hip/hip_runtime.h>
#include <math.h>

// Problem constants (fixed by the reference)
#define N_TOT 200000
#define D_    32
#define MK    1024          // M*K = 64*16
#define EPS_ZERO 1e-5f
#define EPS_DIV  1e-29f

// Tiling
#define BN   64             // n rows per block
#define BMK  128            // (m,k) columns per block
#define NB_N (N_TOT / BN)   // 3125
#define NB_MK (MK / BMK)    // 8

// ---------------------------------------------------------------------------
// Prep: softmax over alpha rows, folded with the affine epilogue.
//   W[mk][d]  = softmax(alpha[mk])[d] / (pos-neg+eps)
//   off[mk]   = (-th[mk] - neg) / (pos-neg+eps)
//   thr[mk]   = EPS_ZERO / (pos-neg+eps)
// Then  B = clip( |T.W| < thr ? off : T.W + off , 0, 1 )
// ---------------------------------------------------------------------------
__global__ __launch_bounds__(256) void prep_kernel(
    const float* __restrict__ alpha, const float* __restrict__ th,
    const float* __restrict__ amb, float* __restrict__ W,
    float* __restrict__ off, float* __restrict__ thr)
{
    int mk = blockIdx.x * 256 + threadIdx.x;
    if (mk >= MK) return;
    float v[D_];
    float mx = -1e30f;
#pragma unroll
    for (int d = 0; d < D_; ++d) { v[d] = alpha[mk * D_ + d]; mx = fmaxf(mx, v[d]); }
    float sum = 0.f;
#pragma unroll
    for (int d = 0; d < D_; ++d) { v[d] = expf(v[d] - mx); sum += v[d]; }
    float pos = amb[mk * 2 + 0];
    float neg = amb[mk * 2 + 1];
    float s = 1.0f / (pos - neg + EPS_DIV);
    float si = s / sum;
#pragma unroll
    for (int d = 0; d < D_; ++d) W[mk * D_ + d] = v[d] * si;
    off[mk] = (0.0f - th[mk] - neg) * s;
    thr[mk] = EPS_ZERO * s;
}

// ---------------------------------------------------------------------------
// Main GEMM-like kernel: out[n][mk] = clip(epilogue(T[n]·W[mk]), 0, 1)
// 256 threads, 64n x 128mk tile, K=32 fully staged in LDS (single stage).
// Per-thread 4n x 8mk register tile.
// ---------------------------------------------------------------------------
__global__ __launch_bounds__(256) void fern_kernel(
    const float* __restrict__ T, const float* __restrict__ W,
    const float* __restrict__ off, const float* __restrict__ thr,
    float* __restrict__ out)
{
    __shared__ float Tl[D_][BN + 4];    // row stride 68 floats = 272 B (16B aligned)
    __shared__ float Wl[D_][BMK + 4];   // row stride 132 floats = 528 B (16B aligned)
    __shared__ float ol[BMK];
    __shared__ float tl[BMK];

    const int bx  = blockIdx.x;
    const int nb  = bx % NB_N;          // n fast-varying: consecutive blocks share W tile
    const int mkb = bx / NB_N;
    const int n0  = nb * BN;
    const int mk0 = mkb * BMK;
    const int tid = threadIdx.x;

    // Stage T tile (64x32 -> transposed [d][n]); 512 float4, 2 per thread
#pragma unroll
    for (int t = 0; t < 2; ++t) {
        int f = tid + t * 256;
        int nl = f >> 3;
        int d4 = (f & 7) * 4;
        float4 v = *(const float4*)(T + (long)(n0 + nl) * D_ + d4);
        Tl[d4 + 0][nl] = v.x; Tl[d4 + 1][nl] = v.y;
        Tl[d4 + 2][nl] = v.z; Tl[d4 + 3][nl] = v.w;
    }
    // Stage W tile (128x32 -> transposed [d][mk]); 1024 float4, 4 per thread
#pragma unroll
    for (int t = 0; t < 4; ++t) {
        int f = tid + t * 256;
        int ml = f >> 3;
        int d4 = (f & 7) * 4;
        float4 v = *(const float4*)(W + (mk0 + ml) * D_ + d4);
        Wl[d4 + 0][ml] = v.x; Wl[d4 + 1][ml] = v.y;
        Wl[d4 + 2][ml] = v.z; Wl[d4 + 3][ml] = v.w;
    }
    if (tid < BMK) { ol[tid] = off[mk0 + tid]; tl[tid] = thr[mk0 + tid]; }
    __syncthreads();

    const int tx = tid & 15;            // 16 columns of threads
    const int ty = tid >> 4;            // 16 rows of threads

    float acc[4][8];
#pragma unroll
    for (int i = 0; i < 4; ++i)
#pragma unroll
        for (int j = 0; j < 8; ++j) acc[i][j] = 0.f;

#pragma unroll
    for (int d = 0; d < D_; ++d) {
        float4 a  = *(const float4*)&Tl[d][ty * 4];
        float4 b0 = *(const float4*)&Wl[d][tx * 4];
        float4 b1 = *(const float4*)&Wl[d][tx * 4 + 64];
        float av[4] = { a.x, a.y, a.z, a.w };
        float bv[8] = { b0.x, b0.y, b0.z, b0.w, b1.x, b1.y, b1.z, b1.w };
#pragma unroll
        for (int i = 0; i < 4; ++i)
#pragma unroll
            for (int j = 0; j < 8; ++j)
                acc[i][j] = fmaf(av[i], bv[j], acc[i][j]);
    }

    // Epilogue: zero-threshold + offset + clamp, then coalesced float4 stores
    float o0[8], t0[8];
#pragma unroll
    for (int j = 0; j < 8; ++j) {
        int ml = tx * 4 + (j >> 2) * 64 + (j & 3);
        o0[j] = ol[ml];
        t0[j] = tl[ml];
    }
#pragma unroll
    for (int i = 0; i < 4; ++i) {
        long base = (long)(n0 + ty * 4 + i) * MK + mk0;
        float r[8];
#pragma unroll
        for (int j = 0; j < 8; ++j) {
            float x = acc[i][j];
            float y = (fabsf(x) < t0[j]) ? o0[j] : (x + o0[j]);
            r[j] = fminf(fmaxf(y, 0.f), 1.f);
        }
        *(float4*)(out + base + tx * 4)      = make_float4(r[0], r[1], r[2], r[3]);
        *(float4*)(out + base + tx * 4 + 64) = make_float4(r[4], r[5], r[6], r[7]);
    }
}

extern "C" void kernel_launch(void* const* d_in, const int* in_sizes, int n_in,
                              void* d_out, int out_size, void* d_ws, size_t ws_size,
                              hipStream_t stream)
{
    const float* T     = (const float*)d_in[0];
    const float* alpha = (const float*)d_in[1];
    const float* th    = (const float*)d_in[2];
    const float* amb   = (const float*)d_in[3];
    float* out = (float*)d_out;

    // Workspace layout: W[MK*D] | off[MK] | thr[MK]  (139,264 bytes total)
    float* W   = (float*)d_ws;
    float* offp = W + MK * D_;
    float* thrp = offp + MK;

    prep_kernel<<<MK / 256, 256, 0, stream>>>(alpha, th, amb, W, offp, thrp);
    fern_kernel<<<NB_N * NB_MK, 256, 0, stream>>>(T, W, offp, thrp, out);
}

// Round 2
// 200.728 us; speedup vs baseline: 1.1747x; 1.1747x over previous
//
#include <hip/hip_runtime.h>
#include <math.h>

// Problem constants (fixed by the reference)
#define N_TOT 200000
#define D_    32
#define MK    1024          // M*K = 64*16
#define EPS_ZERO 1e-5f
#define EPS_DIV  1e-29f

// Tiling
#define BN   64             // n rows per block
#define BMK  256            // (m,k) columns per block
#define NB_N (N_TOT / BN)   // 3125
#define NB_MK (MK / BMK)    // 4

typedef __attribute__((ext_vector_type(8))) short short8;
typedef __attribute__((ext_vector_type(4))) float f32x4;

__device__ __forceinline__ unsigned short f2bf(float x) {
    unsigned int u = __float_as_uint(x);
    u += 0x7FFFu + ((u >> 16) & 1u);          // round-to-nearest-even
    return (unsigned short)(u >> 16);
}
__device__ __forceinline__ float bf2f(unsigned short h) {
    return __uint_as_float(((unsigned int)h) << 16);
}

// ---------------------------------------------------------------------------
// Prep: softmax(alpha) folded with affine epilogue, split into bf16 hi/lo.
//   W[mk][d] = softmax(alpha[mk])[d] / (pos-neg+eps)   -> Whi + Wlo (bf16)
//   ot[mk]   = { (-th-neg)/(pos-neg+eps),  EPS_ZERO/(pos-neg+eps) }
// Then B = clip( |acc| < thr ? off : acc + off, 0, 1 ),  acc = T·W
// ---------------------------------------------------------------------------
__global__ __launch_bounds__(256) void prep_kernel(
    const float* __restrict__ alpha, const float* __restrict__ th,
    const float* __restrict__ amb,
    unsigned short* __restrict__ Whi, unsigned short* __restrict__ Wlo,
    float* __restrict__ ot)
{
    int mk = blockIdx.x * 256 + threadIdx.x;
    if (mk >= MK) return;
    float v[D_];
    float mx = -1e30f;
#pragma unroll
    for (int d = 0; d < D_; ++d) { v[d] = alpha[mk * D_ + d]; mx = fmaxf(mx, v[d]); }
    float sum = 0.f;
#pragma unroll
    for (int d = 0; d < D_; ++d) { v[d] = expf(v[d] - mx); sum += v[d]; }
    float pos = amb[mk * 2 + 0];
    float neg = amb[mk * 2 + 1];
    float s  = 1.0f / (pos - neg + EPS_DIV);
    float si = s / sum;
#pragma unroll
    for (int d = 0; d < D_; ++d) {
        float w = v[d] * si;
        unsigned short h = f2bf(w);
        Whi[mk * D_ + d] = h;
        Wlo[mk * D_ + d] = f2bf(w - bf2f(h));
    }
    ot[2 * mk + 0] = (0.0f - th[mk] - neg) * s;
    ot[2 * mk + 1] = EPS_ZERO * s;
}

// ---------------------------------------------------------------------------
// Main: out[n][mk] = clip(epilogue(T[n]·W[mk]), 0, 1) via bf16 MFMA,
// 3-MFMA hi/lo split for fp32-level accuracy.
// 256 threads = 4 waves; block tile 64n x 256mk; each wave owns 16 n-rows
// and loops 16 mk-tiles of 16 cols (K=32 in a single mfma_16x16x32).
// ---------------------------------------------------------------------------
__global__ __launch_bounds__(256) void fern_mfma(
    const float* __restrict__ T,
    const unsigned short* __restrict__ Whi, const unsigned short* __restrict__ Wlo,
    const float* __restrict__ ot, float* __restrict__ out)
{
    // Row stride 40 shorts = 80 B: bank stride 20 -> conflict-balanced b128 reads
    __shared__ __align__(16) short Thi_l[BN][40];    // 5120 B
    __shared__ __align__(16) short Tlo_l[BN][40];    // 5120 B
    __shared__ __align__(16) short Whi_l[BMK][40];   // 20480 B
    __shared__ __align__(16) short Wlo_l[BMK][40];   // 20480 B
    __shared__ float2 ot_l[BMK];                     // 2048 B  (total 53.2 KB -> 3 blk/CU)

    const int tid = threadIdx.x;
    const int bx  = blockIdx.x;
    const int nb  = bx % NB_N;          // n fastest: consecutive blocks share W tile
    const int mkq = bx / NB_N;
    const int n0  = nb * BN;
    const int mk0 = mkq * BMK;

    // ---- stage T (64 x 32 f32) -> hi/lo bf16, transposed-free [n][k] layout
    {
        int row = tid >> 2;
        int d0  = (tid & 3) * 8;
        const float* src = T + (long)(n0 + row) * D_ + d0;
        float4 v0 = *(const float4*)src;
        float4 v1 = *(const float4*)(src + 4);
        float xs[8] = { v0.x, v0.y, v0.z, v0.w, v1.x, v1.y, v1.z, v1.w };
        short8 vh, vl;
#pragma unroll
        for (int j = 0; j < 8; ++j) {
            unsigned short h = f2bf(xs[j]);
            vh[j] = (short)h;
            vl[j] = (short)f2bf(xs[j] - bf2f(h));
        }
        *(short8*)&Thi_l[row][d0] = vh;
        *(short8*)&Tlo_l[row][d0] = vl;
    }
    // ---- stage W (256 x 32 bf16, hi+lo): 16B chunks, 4 per thread each
#pragma unroll
    for (int i = 0; i < 4; ++i) {
        int f   = tid + i * 256;
        int col = f >> 2;
        int k0  = (f & 3) * 8;
        *(short8*)&Whi_l[col][k0] = *(const short8*)(Whi + (long)(mk0 + col) * D_ + k0);
        *(short8*)&Wlo_l[col][k0] = *(const short8*)(Wlo + (long)(mk0 + col) * D_ + k0);
    }
    ot_l[tid] = *(const float2*)(ot + 2 * (mk0 + tid));
    __syncthreads();

    const int lane = tid & 63;
    const int wid  = tid >> 6;          // wave owns rows [wid*16, wid*16+16)
    const int lc   = lane & 15;         // fragment row (A) / col (B/C)
    const int lk   = lane >> 4;         // k-group (8 consecutive k per lane)

    short8 ahi = *(const short8*)&Thi_l[wid * 16 + lc][lk * 8];
    short8 alo = *(const short8*)&Tlo_l[wid * 16 + lc][lk * 8];

    // C/D layout: col = lane&15, row = (lane>>4)*4 + j   [measured m89/m91]
    long rowbase = ((long)(n0 + wid * 16 + lk * 4)) * MK + mk0 + lc;

#pragma unroll 4
    for (int t = 0; t < 16; ++t) {
        short8 bhi = *(const short8*)&Whi_l[t * 16 + lc][lk * 8];
        short8 blo = *(const short8*)&Wlo_l[t * 16 + lc][lk * 8];
        f32x4 acc = { 0.f, 0.f, 0.f, 0.f };
        acc = __builtin_amdgcn_mfma_f32_16x16x32_bf16(ahi, bhi, acc, 0, 0, 0);
        acc = __builtin_amdgcn_mfma_f32_16x16x32_bf16(alo, bhi, acc, 0, 0, 0);
        acc = __builtin_amdgcn_mfma_f32_16x16x32_bf16(ahi, blo, acc, 0, 0, 0);

        float2 o2 = ot_l[t * 16 + lc];   // {off, thr} — same col for all 4 rows
        float* po = out + rowbase + t * 16;
#pragma unroll
        for (int j = 0; j < 4; ++j) {
            float x = acc[j];
            float y = (fabsf(x) < o2.y) ? o2.x : (x + o2.x);
            po[j * MK] = fminf(fmaxf(y, 0.f), 1.f);
        }
    }
}

extern "C" void kernel_launch(void* const* d_in, const int* in_sizes, int n_in,
                              void* d_out, int out_size, void* d_ws, size_t ws_size,
                              hipStream_t stream)
{
    const float* T     = (const float*)d_in[0];
    const float* alpha = (const float*)d_in[1];
    const float* th    = (const float*)d_in[2];
    const float* amb   = (const float*)d_in[3];
    float* out = (float*)d_out;

    // ws layout: Whi[32768 u16] | Wlo[32768 u16] | ot[1024 float2]  = 139,264 B
    unsigned short* Whi = (unsigned short*)d_ws;
    unsigned short* Wlo = Whi + MK * D_;
    float* ot = (float*)(Wlo + MK * D_);

    prep_kernel<<<MK / 256, 256, 0, stream>>>(alpha, th, amb, Whi, Wlo, ot);
    fern_mfma<<<NB_N * NB_MK, 256, 0, stream>>>(T, Whi, Wlo, ot, out);
}

// Round 3
// 199.832 us; speedup vs baseline: 1.1800x; 1.0045x over previous
//
#include <hip/hip_runtime.h>
#include <math.h>

// Problem constants (fixed by the reference)
#define N_TOT 200000
#define D_    32
#define MK    1024          // M*K = 64*16
#define EPS_ZERO 1e-5f
#define EPS_DIV  1e-29f

// Tiling
#define BN   64             // n rows per block
#define BMK  256            // (m,k) columns per block
#define NB_N (N_TOT / BN)   // 3125
#define NB_MK (MK / BMK)    // 4

typedef __attribute__((ext_vector_type(8))) short short8;
typedef __attribute__((ext_vector_type(4))) float f32x4;

__device__ __forceinline__ unsigned short f2bf(float x) {
    unsigned int u = __float_as_uint(x);
    u += 0x7FFFu + ((u >> 16) & 1u);          // round-to-nearest-even
    return (unsigned short)(u >> 16);
}
__device__ __forceinline__ float bf2f(unsigned short h) {
    return __uint_as_float(((unsigned int)h) << 16);
}

// ---------------------------------------------------------------------------
// Prep: softmax(alpha) folded with affine epilogue, split into bf16 hi/lo.
//   W[mk][d] = softmax(alpha[mk])[d] / (pos-neg+eps)   -> Whi + Wlo (bf16)
//   ot[mk]   = { (-th-neg)/(pos-neg+eps),  EPS_ZERO/(pos-neg+eps) }
// Then B = clip( |acc| < thr ? off : acc + off, 0, 1 ),  acc = T·W
// ---------------------------------------------------------------------------
__global__ __launch_bounds__(256) void prep_kernel(
    const float* __restrict__ alpha, const float* __restrict__ th,
    const float* __restrict__ amb,
    unsigned short* __restrict__ Whi, unsigned short* __restrict__ Wlo,
    float* __restrict__ ot)
{
    int mk = blockIdx.x * 256 + threadIdx.x;
    if (mk >= MK) return;
    float v[D_];
    float mx = -1e30f;
#pragma unroll
    for (int d = 0; d < D_; ++d) { v[d] = alpha[mk * D_ + d]; mx = fmaxf(mx, v[d]); }
    float sum = 0.f;
#pragma unroll
    for (int d = 0; d < D_; ++d) { v[d] = expf(v[d] - mx); sum += v[d]; }
    float pos = amb[mk * 2 + 0];
    float neg = amb[mk * 2 + 1];
    float s  = 1.0f / (pos - neg + EPS_DIV);
    float si = s / sum;
#pragma unroll
    for (int d = 0; d < D_; ++d) {
        float w = v[d] * si;
        unsigned short h = f2bf(w);
        Whi[mk * D_ + d] = h;
        Wlo[mk * D_ + d] = f2bf(w - bf2f(h));
    }
    ot[2 * mk + 0] = (0.0f - th[mk] - neg) * s;
    ot[2 * mk + 1] = EPS_ZERO * s;
}

// ---------------------------------------------------------------------------
// Main: out[n][mk] = clip(epilogue(T[n]·W[mk]), 0, 1) via bf16 MFMA,
// 3-MFMA hi/lo split for fp32-level accuracy.
// 256 threads = 4 waves; block tile 64n x 256mk; each wave owns 16 n-rows
// and loops 16 mk-tiles of 16 cols (K=32 in a single mfma_16x16x32).
// ---------------------------------------------------------------------------
__global__ __launch_bounds__(256) void fern_mfma(
    const float* __restrict__ T,
    const unsigned short* __restrict__ Whi, const unsigned short* __restrict__ Wlo,
    const float* __restrict__ ot, float* __restrict__ out)
{
    // Row stride 40 shorts = 80 B: bank stride 20 -> conflict-balanced b128 reads
    __shared__ __align__(16) short Thi_l[BN][40];    // 5120 B
    __shared__ __align__(16) short Tlo_l[BN][40];    // 5120 B
    __shared__ __align__(16) short Whi_l[BMK][40];   // 20480 B
    __shared__ __align__(16) short Wlo_l[BMK][40];   // 20480 B
    __shared__ float2 ot_l[BMK];                     // 2048 B  (total 53.2 KB -> 3 blk/CU)

    const int tid = threadIdx.x;
    const int bx  = blockIdx.x;
    const int nb  = bx % NB_N;          // n fastest: consecutive blocks share W tile
    const int mkq = bx / NB_N;
    const int n0  = nb * BN;
    const int mk0 = mkq * BMK;

    // ---- stage T (64 x 32 f32) -> hi/lo bf16, transposed-free [n][k] layout
    {
        int row = tid >> 2;
        int d0  = (tid & 3) * 8;
        const float* src = T + (long)(n0 + row) * D_ + d0;
        float4 v0 = *(const float4*)src;
        float4 v1 = *(const float4*)(src + 4);
        float xs[8] = { v0.x, v0.y, v0.z, v0.w, v1.x, v1.y, v1.z, v1.w };
        short8 vh, vl;
#pragma unroll
        for (int j = 0; j < 8; ++j) {
            unsigned short h = f2bf(xs[j]);
            vh[j] = (short)h;
            vl[j] = (short)f2bf(xs[j] - bf2f(h));
        }
        *(short8*)&Thi_l[row][d0] = vh;
        *(short8*)&Tlo_l[row][d0] = vl;
    }
    // ---- stage W (256 x 32 bf16, hi+lo): 16B chunks, 4 per thread each
#pragma unroll
    for (int i = 0; i < 4; ++i) {
        int f   = tid + i * 256;
        int col = f >> 2;
        int k0  = (f & 3) * 8;
        *(short8*)&Whi_l[col][k0] = *(const short8*)(Whi + (long)(mk0 + col) * D_ + k0);
        *(short8*)&Wlo_l[col][k0] = *(const short8*)(Wlo + (long)(mk0 + col) * D_ + k0);
    }
    ot_l[tid] = *(const float2*)(ot + 2 * (mk0 + tid));
    __syncthreads();

    const int lane = tid & 63;
    const int wid  = tid >> 6;          // wave owns rows [wid*16, wid*16+16)
    const int lc   = lane & 15;         // fragment row (A) / col (B/C)
    const int lk   = lane >> 4;         // k-group (8 consecutive k per lane)

    short8 ahi = *(const short8*)&Thi_l[wid * 16 + lc][lk * 8];
    short8 alo = *(const short8*)&Tlo_l[wid * 16 + lc][lk * 8];

    // C/D layout: col = lane&15, row = (lane>>4)*4 + j   [measured m89/m91]
    long rowbase = ((long)(n0 + wid * 16 + lk * 4)) * MK + mk0 + lc;

#pragma unroll 4
    for (int t = 0; t < 16; ++t) {
        short8 bhi = *(const short8*)&Whi_l[t * 16 + lc][lk * 8];
        short8 blo = *(const short8*)&Wlo_l[t * 16 + lc][lk * 8];
        f32x4 acc = { 0.f, 0.f, 0.f, 0.f };
        acc = __builtin_amdgcn_mfma_f32_16x16x32_bf16(ahi, bhi, acc, 0, 0, 0);
        acc = __builtin_amdgcn_mfma_f32_16x16x32_bf16(alo, bhi, acc, 0, 0, 0);
        acc = __builtin_amdgcn_mfma_f32_16x16x32_bf16(ahi, blo, acc, 0, 0, 0);

        float2 o2 = ot_l[t * 16 + lc];   // {off, thr} — same col for all 4 rows
        float* po = out + rowbase + t * 16;
#pragma unroll
        for (int j = 0; j < 4; ++j) {
            float x = acc[j];
            float y = (fabsf(x) < o2.y) ? o2.x : (x + o2.x);
            po[j * MK] = fminf(fmaxf(y, 0.f), 1.f);
        }
    }
}

extern "C" void kernel_launch(void* const* d_in, const int* in_sizes, int n_in,
                              void* d_out, int out_size, void* d_ws, size_t ws_size,
                              hipStream_t stream)
{
    const float* T     = (const float*)d_in[0];
    const float* alpha = (const float*)d_in[1];
    const float* th    = (const float*)d_in[2];
    const float* amb   = (const float*)d_in[3];
    float* out = (float*)d_out;

    // ws layout: Whi[32768 u16] | Wlo[32768 u16] | ot[1024 float2]  = 139,264 B
    unsigned short* Whi = (unsigned short*)d_ws;
    unsigned short* Wlo = Whi + MK * D_;
    float* ot = (float*)(Wlo + MK * D_);

    prep_kernel<<<MK / 256, 256, 0, stream>>>(alpha, th, amb, Whi, Wlo, ot);
    fern_mfma<<<NB_N * NB_MK, 256, 0, stream>>>(T, Whi, Wlo, ot, out);
}